// Round 1
// 269.563 us; speedup vs baseline: 1.0185x; 1.0185x over previous
//
#include <hip/hip_runtime.h>
#include <hip/hip_fp16.h>

// HungarianMatcher cost C[16,1500,2400] = 5*L1 + focal_class + 2*(-GIoU)
// v2 structure (vs 274us version):
//  - targets live in REGISTERS (4 consecutive per thread), loaded once from
//    global (tboxes = 38KB, L1/L2 resident) -> removes 3 of 4 LDS reads/elem
//  - focal table transposed to [class][q] fp16, rows padded to 40B so one
//    ds_read_b64 fetches 4 queries' class cost for a target (16 b64/thread
//    total vs 256 ds_read before); cc+2 folded into the table
//  - consecutive-target ownership -> global_store_dwordx4 (4x fewer stores)
//  - query boxes are block-uniform -> s_load_dwordx4, no VGPR cost
// Floors: store BW ~37us (230MB), VALU ~25us (~30 ops/elem).

namespace {
constexpr int kBS = 16, kQ = 1500, kK = 256, kNT = 150;
constexpr int kT  = kBS * kNT;   // 2400 targets
constexpr int kQB = 16;          // queries per block
constexpr int kTT = 1024;        // target tile (1024,1024,352)
constexpr int kTiles = 3;
constexpr float kAlpha = 0.25f;
constexpr float kEps   = 1e-8f;
}

__global__ __launch_bounds__(256, 4)
void matcher_cost_kernel(const float* __restrict__ logits,   // [N,256]
                         const float* __restrict__ pboxes,   // [N,4] cxcywh
                         const float* __restrict__ tboxes,   // [T,4] cxcywh
                         const int*   __restrict__ tids,     // [T]
                         float* __restrict__ out)            // [N,T]
{
    // [class][q/2] half2, row stride 10 half2 = 40B (cols 8,9 pad).
    // gather addr = cid*40 + qg*8 : 8B-aligned, row stride = 10 dwords
    // -> 16 distinct bank-start positions for random cid (~4-way, cheap).
    __shared__ __align__(16) __half2 s_fcl[kK][10];   // 10.25 KB

    const int tid = threadIdx.x;
    const int n0  = blockIdx.x * kQB;
    const int t0  = blockIdx.y * kTT;
    const int tsz = min(kTT, kT - t0);

    // ---- issue target loads first (4 consecutive targets per thread) ----
    const int  tbase  = t0 + (tid << 2);
    const bool active = (tid << 2) < tsz;          // tsz is a multiple of 4
    float4 tb[4];
    int4 ci = make_int4(0, 0, 0, 0);
    if (active) {
        const float4* tb4 = reinterpret_cast<const float4*>(tboxes);
        ci = *reinterpret_cast<const int4*>(tids + tbase);
#pragma unroll
        for (int e = 0; e < 4; ++e) tb[e] = tb4[tbase + e];
    } else {
#pragma unroll
        for (int e = 0; e < 4; ++e) tb[e] = make_float4(0.f, 0.f, 1.f, 1.f);
    }

    // ---- focal class-cost table, transposed [class][q], stores cc+2 ----
    {
        const float* lrow = logits + n0 * kK + tid;   // thread = class
#pragma unroll
        for (int qp = 0; qp < kQB / 2; ++qp) {
            float c[2];
#pragma unroll
            for (int j = 0; j < 2; ++j) {
                const float x   = lrow[(2 * qp + j) * kK];
                const float p   = __builtin_amdgcn_rcpf(1.0f + __expf(-x));
                const float omp = 1.0f - p;
                c[j] = -kAlpha * omp * omp * __logf(p + kEps)
                     + (1.0f - kAlpha) * p * p * __logf(omp + kEps) + 2.0f;
            }
            s_fcl[tid][qp] = __floats2half2_rn(c[0], c[1]);
        }
    }

    __syncthreads();          // the only barrier; LDS read-only below
    if (!active) return;      // tail tile: idle threads exit after barrier

    // ---- per-target derived registers (loop-invariant across q) ----
    int   cid[4];
    float bcx[4], bcy[4], bw[4], bh[4], bx1[4], bx2[4], by1[4], by2[4], bar[4];
    cid[0] = ci.x; cid[1] = ci.y; cid[2] = ci.z; cid[3] = ci.w;
#pragma unroll
    for (int e = 0; e < 4; ++e) {
        bcx[e] = tb[e].x; bcy[e] = tb[e].y; bw[e] = tb[e].z; bh[e] = tb[e].w;
        bx1[e] = bcx[e] - 0.5f * bw[e];  bx2[e] = bcx[e] + 0.5f * bw[e];
        by1[e] = bcy[e] - 0.5f * bh[e];  by2[e] = bcy[e] + 0.5f * bh[e];
        bar[e] = bw[e] * bh[e];
    }

    float* __restrict__ orow = out + (size_t)n0 * kT + tbase;

#pragma unroll
    for (int qg = 0; qg < 4; ++qg) {
        // one b64 per target fetches class cost for 4 queries
        uint2 ccr[4];
#pragma unroll
        for (int e = 0; e < 4; ++e)
            ccr[e] = *reinterpret_cast<const uint2*>(&s_fcl[cid[e]][qg * 2]);

#pragma unroll
        for (int qi = 0; qi < 4; ++qi) {
            const int q = qg * 4 + qi;
            // block-uniform query box -> scalar load
            const float4 pb = *reinterpret_cast<const float4*>(pboxes + (n0 + q) * 4);
            const float pcx = pb.x, pcy = pb.y, pw = pb.z, ph = pb.w;
            const float px1 = pcx - 0.5f * pw, px2 = pcx + 0.5f * pw;
            const float py1 = pcy - 0.5f * ph, py2 = pcy + 0.5f * ph;
            const float parea = pw * ph;

            float res[4];
#pragma unroll
            for (int e = 0; e < 4; ++e) {
                const unsigned u   = (qi < 2) ? ccr[e].x : ccr[e].y;   // qi compile-time
                const __half2  h2  = *reinterpret_cast<const __half2*>(&u);
                const float ccp2   = (qi & 1) ? __high2float(h2) : __low2float(h2);
                // L1 cost (cxcywh space)
                const float cb = fabsf(pcx - bcx[e]) + fabsf(pcy - bcy[e])
                               + fabsf(pw  - bw[e])  + fabsf(ph  - bh[e]);
                // overlap; enclose via identity ew = pw+bw-ow
                const float ow = fminf(px2, bx2[e]) - fmaxf(px1, bx1[e]);
                const float oh = fminf(py2, by2[e]) - fmaxf(py1, by1[e]);
                const float iw = fmaxf(ow, 0.0f), ih = fmaxf(oh, 0.0f);
                const float ew = (pw + bw[e]) - ow, eh = (ph + bh[e]) - oh;
                const float inter = iw * ih;
                const float uni   = (parea + bar[e]) - inter;
                const float ear   = ew * eh;
                // out = 5cb + (cc+2) - 2*(inter*ear + uni*uni)/(uni*ear)
                const float rr   = __builtin_amdgcn_rcpf(uni * ear);
                const float frac = fmaf(uni, uni, inter * ear) * rr;
                res[e] = fmaf(5.0f, cb, ccp2) - 2.0f * frac;
            }
            *reinterpret_cast<float4*>(orow + (size_t)q * kT) =
                make_float4(res[0], res[1], res[2], res[3]);
        }
    }
}

extern "C" void kernel_launch(void* const* d_in, const int* in_sizes, int n_in,
                              void* d_out, int out_size, void* d_ws, size_t ws_size,
                              hipStream_t stream) {
    const float* logits = (const float*)d_in[0];   // [16,1500,256]
    const float* pboxes = (const float*)d_in[1];   // [16,1500,4]
    const float* tboxes = (const float*)d_in[2];   // [2400,4]
    const int*   tids   = (const int*)d_in[3];     // [2400]
    float* out = (float*)d_out;                    // [16,1500,2400] fp32

    dim3 grid(kBS * kQ / kQB, kTiles);   // 1500 x 3
    dim3 block(256);
    hipLaunchKernelGGL(matcher_cost_kernel, grid, block, 0, stream,
                       logits, pboxes, tboxes, tids, out);
}